// Round 1
// baseline (112.035 us; speedup 1.0000x reference)
//
#include <hip/hip_runtime.h>

// QuantumMeasurement: exp[b,q] = sum_i (re^2+im^2)[b,i] * (-1)^{bit_{9-q}(i)}
// Pauli-Z matrices are diagonal with signs given by the bit pattern, so we
// never read the 80 MB observable tensor. Pure streaming reduction, 64 MB in.

#define BATCH 8192
#define DIM   1024
#define NQ    10

__global__ __launch_bounds__(256) void qmeas_kernel(
    const float* __restrict__ sre,
    const float* __restrict__ sim,
    float* __restrict__ out)
{
    // one 64-lane wave per batch row
    const int row  = (int)((blockIdx.x * blockDim.x + threadIdx.x) >> 6);
    const int lane = (int)(threadIdx.x & 63);

    const float4* __restrict__ rowR = (const float4*)(sre + (size_t)row * DIM);
    const float4* __restrict__ rowI = (const float4*)(sim + (size_t)row * DIM);

    // element index i = 4*(lane + 64*it) + c
    //   bits 0,1 of i = c        -> qubits 9,8  (intra-float4 combos)
    //   bits 2..7 of i = lane    -> qubits 7..2 (butterfly diff extraction)
    //   bits 8,9 of i = it       -> qubits 1,0  (compile-time signs)
    float tot = 0.f, a8 = 0.f, a9 = 0.f, aq0 = 0.f, aq1 = 0.f;
#pragma unroll
    for (int it = 0; it < 4; ++it) {
        float4 r = rowR[lane + 64 * it];
        float4 m = rowI[lane + 64 * it];
        float p0 = fmaf(r.x, r.x, m.x * m.x);
        float p1 = fmaf(r.y, r.y, m.y * m.y);
        float p2 = fmaf(r.z, r.z, m.z * m.z);
        float p3 = fmaf(r.w, r.w, m.w * m.w);
        float a = p0 + p1, b = p2 + p3;   // pairs over bit0
        float e = p0 - p1, f = p2 - p3;
        float s = a + b;                  // all 4
        a9  += e + f;                     // qubit 9: + - + -
        a8  += a - b;                     // qubit 8: + + - -
        tot += s;
        aq1 += (it & 1) ? -s : s;         // qubit 1: bit 8 of i
        aq0 += (it & 2) ? -s : s;         // qubit 0: bit 9 of i
    }

    // plain 64-lane sums for the four lane-independent accumulators
#pragma unroll
    for (int d = 1; d < 64; d <<= 1) {
        a8  += __shfl_xor(a8,  d);
        a9  += __shfl_xor(a9,  d);
        aq0 += __shfl_xor(aq0, d);
        aq1 += __shfl_xor(aq1, d);
    }

    // Walsh-style butterfly on tot: at level k capture the signed difference
    // for lane-bit k (qubit 7-k), keep summing for higher levels. Lane 0 has
    // all bits 0, so every dk[k] at lane 0 carries the correct global sign.
    float dk[6];
    float s = tot;
#pragma unroll
    for (int k = 0; k < 6; ++k) {
        float y = __shfl_xor(s, 1 << k);
        dk[k] = s - y;
        s += y;
    }
#pragma unroll
    for (int k = 0; k < 6; ++k) {
#pragma unroll
        for (int m2 = k + 1; m2 < 6; ++m2)
            dk[k] += __shfl_xor(dk[k], 1 << m2);
    }

    if (lane == 0) {
        float* o = out + (size_t)row * NQ;
        o[0] = aq0;    // qubit 0
        o[1] = aq1;    // qubit 1
        o[2] = dk[5];  // qubit 2 <- lane bit 5
        o[3] = dk[4];
        o[4] = dk[3];
        o[5] = dk[2];
        o[6] = dk[1];
        o[7] = dk[0];  // qubit 7 <- lane bit 0
        o[8] = a8;     // qubit 8
        o[9] = a9;     // qubit 9
    }
}

extern "C" void kernel_launch(void* const* d_in, const int* in_sizes, int n_in,
                              void* d_out, int out_size, void* d_ws, size_t ws_size,
                              hipStream_t stream) {
    const float* sre = (const float*)d_in[0];
    const float* sim = (const float*)d_in[1];
    // d_in[2] (pauli_z_obs) is intentionally unused: diagonal signs computed analytically.
    float* out = (float*)d_out;

    // 4 waves (rows) per 256-thread block
    dim3 grid(BATCH / 4), block(256);
    qmeas_kernel<<<grid, block, 0, stream>>>(sre, sim, out);
}